// Round 1
// baseline (246.292 us; speedup 1.0000x reference)
//
#include <hip/hip_runtime.h>
#include <math.h>

// Selective SSM (Mamba-style) chunked-scan implementation.
//
// Shapes: BATCH=4, SEQ=2048, D=768, N=16.
// Pipeline:
//   k_proj : delta[b,l] = softplus(p + u.q), B/C[b,l,n] = W_{B,C} @ u   (wave per row)
//   k_scan : per (b,chunk,d) thread, 16 n-states in registers; local scan with
//            x0=0 over CHUNK=64 steps; writes local y and chunk-end state.
//            deltaA = exp(delta*A) computed as exp2(A*log2e * delta).
//   k_carry: carry_{c+1} = exp2(A2 * sum_chunk(delta)) * carry_c + xend_c
//            (stores carry entering each chunk in-place over xend)
//   k_fix  : y[b,l,d] += sum_n exp2(A2[n]*cumsum(delta)) * carry[n] * C[l,n]
//            early uniform break when cumsum(delta) > 183 (all exp2 underflow,
//            valid because max_n A[d,n] = -0.5 by construction).

#define BATCH 4
#define SEQ   2048
#define DDIM  768
#define NST   16
#define CHUNK 64
#define NC    (SEQ / CHUNK)      // 32
#define ROWS  (BATCH * SEQ)      // 8192
#define DT    (DDIM / 128)       // 6 d-tiles of 128
#define LOG2E 1.4426950408889634f

__device__ __forceinline__ float fexp2(float x) {
#if __has_builtin(__builtin_amdgcn_exp2f)
  return __builtin_amdgcn_exp2f(x);
#else
  return exp2f(x);
#endif
}

// ---------------------------------------------------------------- k_proj ----
// One wave (64 lanes) per row r = b*SEQ + l. 33 dot products of length 768.
__global__ __launch_bounds__(256) void k_proj(
    const float* __restrict__ u, const float* __restrict__ W_B,
    const float* __restrict__ W_C, const float* __restrict__ q_delta,
    const float* __restrict__ p_delta, float* __restrict__ delta,
    float* __restrict__ Bm, float* __restrict__ Cm) {
  const int gtid = blockIdx.x * 256 + threadIdx.x;
  const int row  = gtid >> 6;   // 0..8191 (grid sized exactly)
  const int lane = gtid & 63;

  const float* urow = u + (size_t)row * DDIM;
  float uv[12];
#pragma unroll
  for (int k = 0; k < 12; ++k) uv[k] = urow[lane + 64 * k];

  float mine = 0.0f;
#pragma unroll
  for (int j = 0; j < 33; ++j) {
    const float* w = (j < 16) ? (W_B + j * DDIM)
                   : (j < 32) ? (W_C + (j - 16) * DDIM)
                              : q_delta;
    float s = 0.0f;
#pragma unroll
    for (int k = 0; k < 12; ++k) s = fmaf(uv[k], w[lane + 64 * k], s);
#pragma unroll
    for (int off = 32; off >= 1; off >>= 1) s += __shfl_xor(s, off);
    if (lane == j) mine = s;
  }

  if (lane < 16) {
    Bm[row * NST + lane] = mine;
  } else if (lane < 32) {
    Cm[row * NST + (lane - 16)] = mine;
  } else if (lane == 32) {
    const float z  = p_delta[0] + mine;
    const float sp = fmaxf(z, 0.0f) + log1pf(expf(-fabsf(z)));
    delta[row] = sp;
  }
}

// ---------------------------------------------------------------- k_scan ----
// Block = 128 threads = one d-tile of one (b, chunk). Thread owns d, 16 states.
__global__ __launch_bounds__(128) void k_scan(
    const float* __restrict__ u, const float* __restrict__ A,
    const float* __restrict__ delta, const float* __restrict__ Bm,
    const float* __restrict__ Cm, float* __restrict__ y,
    float* __restrict__ xend) {
  __shared__ float sdelta[CHUNK];
  __shared__ float Bs[CHUNK * NST];
  __shared__ float Cs[CHUNK * NST];

  const int dt = blockIdx.x % DT;
  const int c  = (blockIdx.x / DT) % NC;
  const int b  = blockIdx.x / (DT * NC);
  const int d  = dt * 128 + threadIdx.x;
  const int r0 = b * SEQ + c * CHUNK;

  for (int i = threadIdx.x; i < CHUNK * NST; i += 128) {
    Bs[i] = Bm[r0 * NST + i];
    Cs[i] = Cm[r0 * NST + i];
  }
  if (threadIdx.x < CHUNK) sdelta[threadIdx.x] = delta[r0 + threadIdx.x];
  __syncthreads();

  float A2[NST];
#pragma unroll
  for (int n = 0; n < NST; ++n) A2[n] = A[d * NST + n] * LOG2E;
  float x[NST];
#pragma unroll
  for (int n = 0; n < NST; ++n) x[n] = 0.0f;

  const float* up = u + (size_t)r0 * DDIM + d;
  float*       yp = y + (size_t)r0 * DDIM + d;

  for (int i = 0; i < CHUNK; ++i) {
    const float dl = sdelta[i];
    const float du = dl * up[i * DDIM];

    float bv[NST], cv[NST];
    {
      const float4* Bp = (const float4*)(Bs + i * NST);
      const float4* Cp = (const float4*)(Cs + i * NST);
#pragma unroll
      for (int q = 0; q < 4; ++q) {
        const float4 tb = Bp[q];
        bv[4 * q + 0] = tb.x; bv[4 * q + 1] = tb.y;
        bv[4 * q + 2] = tb.z; bv[4 * q + 3] = tb.w;
        const float4 tc = Cp[q];
        cv[4 * q + 0] = tc.x; cv[4 * q + 1] = tc.y;
        cv[4 * q + 2] = tc.z; cv[4 * q + 3] = tc.w;
      }
    }

    float acc[4] = {0.0f, 0.0f, 0.0f, 0.0f};
#pragma unroll
    for (int n = 0; n < NST; ++n) {
      const float dA = fexp2(A2[n] * dl);
      x[n] = fmaf(dA, x[n], du * bv[n]);
      acc[n & 3] = fmaf(x[n], cv[n], acc[n & 3]);
    }
    yp[i * DDIM] = (acc[0] + acc[1]) + (acc[2] + acc[3]);
  }

  float4* xe = (float4*)(xend + ((size_t)((b * NC + c) * DDIM + d)) * NST);
  xe[0] = make_float4(x[0], x[1], x[2], x[3]);
  xe[1] = make_float4(x[4], x[5], x[6], x[7]);
  xe[2] = make_float4(x[8], x[9], x[10], x[11]);
  xe[3] = make_float4(x[12], x[13], x[14], x[15]);
}

// --------------------------------------------------------------- k_carry ----
// Block = 256 threads = (16 d) x (16 n) for one batch's d-tile. Sequential
// over 32 chunks. Rewrites xend[c] with the carry ENTERING chunk c.
__global__ __launch_bounds__(256) void k_carry(
    const float* __restrict__ A, const float* __restrict__ delta,
    float* __restrict__ xend) {
  __shared__ float Ds[NC];
  const int b    = blockIdx.x / (DDIM / 16);
  const int dblk = blockIdx.x % (DDIM / 16);
  const int tid  = threadIdx.x;

  {
    float s = 0.0f;
    const float* dp = delta + b * SEQ + tid * 8;
#pragma unroll
    for (int k = 0; k < 8; ++k) s += dp[k];
    s += __shfl_xor(s, 1);
    s += __shfl_xor(s, 2);
    s += __shfl_xor(s, 4);
    if ((tid & 7) == 0) Ds[tid >> 3] = s;   // 8 threads per chunk of 64
  }
  __syncthreads();

  const int n = tid & 15;
  const int d = dblk * 16 + (tid >> 4);
  const float A2 = A[d * NST + n] * LOG2E;

  float carry = 0.0f;
  for (int c = 0; c < NC; ++c) {
    const size_t idx = ((size_t)((b * NC + c) * DDIM + d)) * NST + n;
    const float xe = xend[idx];
    const float P  = fexp2(A2 * Ds[c]);
    xend[idx] = carry;               // carry entering chunk c
    carry = fmaf(P, carry, xe);
  }
}

// ----------------------------------------------------------------- k_fix ----
// Adds carry-in correction to y for chunks 1..NC-1. Uniform early break when
// cumulative delta > 183 (exp2 argument < -132 for every A <= -0.5).
__global__ __launch_bounds__(128) void k_fix(
    const float* __restrict__ A, const float* __restrict__ delta,
    const float* __restrict__ Cm, const float* __restrict__ xend,
    float* __restrict__ y) {
  const int dt = blockIdx.x % DT;
  const int c  = (blockIdx.x / DT) % (NC - 1) + 1;
  const int b  = blockIdx.x / (DT * (NC - 1));
  const int d  = dt * 128 + threadIdx.x;

  float A2[NST], carry[NST];
#pragma unroll
  for (int n = 0; n < NST; ++n) A2[n] = A[d * NST + n] * LOG2E;
  {
    const float4* cp =
        (const float4*)(xend + ((size_t)((b * NC + c) * DDIM + d)) * NST);
#pragma unroll
    for (int q = 0; q < 4; ++q) {
      const float4 t = cp[q];
      carry[4 * q + 0] = t.x; carry[4 * q + 1] = t.y;
      carry[4 * q + 2] = t.z; carry[4 * q + 3] = t.w;
    }
  }

  const int r0 = b * SEQ + c * CHUNK;
  float* yp = y + (size_t)r0 * DDIM + d;

  float dS = 0.0f;
  for (int i = 0; i < CHUNK; ++i) {
    dS += delta[r0 + i];
    if (dS > 183.0f) break;   // uniform across block (delta shared)
    float cv[NST];
    {
      const float4* Cp = (const float4*)(Cm + (size_t)(r0 + i) * NST);
#pragma unroll
      for (int q = 0; q < 4; ++q) {
        const float4 t = Cp[q];
        cv[4 * q + 0] = t.x; cv[4 * q + 1] = t.y;
        cv[4 * q + 2] = t.z; cv[4 * q + 3] = t.w;
      }
    }
    float acc[4] = {0.0f, 0.0f, 0.0f, 0.0f};
#pragma unroll
    for (int n = 0; n < NST; ++n) {
      const float e = fexp2(A2[n] * dS);
      acc[n & 3] = fmaf(e * carry[n], cv[n], acc[n & 3]);
    }
    yp[i * DDIM] += (acc[0] + acc[1]) + (acc[2] + acc[3]);
  }
}

// ------------------------------------------------------------------ launch --
extern "C" void kernel_launch(void* const* d_in, const int* in_sizes, int n_in,
                              void* d_out, int out_size, void* d_ws,
                              size_t ws_size, hipStream_t stream) {
  const float* u       = (const float*)d_in[0];
  const float* A       = (const float*)d_in[1];
  const float* W_B     = (const float*)d_in[2];
  const float* W_C     = (const float*)d_in[3];
  const float* q_delta = (const float*)d_in[4];
  const float* p_delta = (const float*)d_in[5];
  float* y = (float*)d_out;

  float* ws    = (float*)d_ws;
  float* delta = ws;                 // ROWS                    = 8192
  float* Bm    = ws + 8192;          // ROWS*NST                = 131072
  float* Cm    = ws + 139264;        // ROWS*NST                = 131072
  float* xend  = ws + 270336;        // BATCH*NC*DDIM*NST       = 1572864
  // total: 1,843,200 floats = 7.37 MB of workspace

  hipLaunchKernelGGL(k_proj, dim3(ROWS / 4), dim3(256), 0, stream,
                     u, W_B, W_C, q_delta, p_delta, delta, Bm, Cm);
  hipLaunchKernelGGL(k_scan, dim3(BATCH * NC * DT), dim3(128), 0, stream,
                     u, A, delta, Bm, Cm, y, xend);
  hipLaunchKernelGGL(k_carry, dim3(BATCH * (DDIM / 16)), dim3(256), 0, stream,
                     A, delta, xend);
  hipLaunchKernelGGL(k_fix, dim3(BATCH * (NC - 1) * DT), dim3(128), 0, stream,
                     A, delta, Cm, xend, y);
}

// Round 2
// 182.010 us; speedup vs baseline: 1.3532x; 1.3532x over previous
//
#include <hip/hip_runtime.h>
#include <math.h>

// Selective SSM (Mamba-style) chunked-scan implementation, round 2.
//
// Shapes: BATCH=4, SEQ=2048, D=768, N=16.
// Pipeline:
//   k_proj : delta[b,l] = softplus(p + u.q), B/C[b,l,n] = W_{B,C} @ u
//            Block = 32 rows x 8 K-splits (256 thr). K tiled 8x96; W slice
//            staged in LDS (broadcast ds_read_b128), u read as float4 via L1.
//            Reduce: shfl_xor(32) + cross-wave LDS tree. No long shuffle
//            chains, no per-row re-fetch of W from L2.
//   k_scan : per (b,chunk,d) thread, 16 n-states in registers; local scan with
//            x0=0 over CHUNK steps; writes local y and chunk-end state.
//   k_carry: carry_{c+1} = exp2(A2 * sum_chunk(delta)) * carry_c + xend_c
//   k_fix  : y += sum_n exp2(A2[n]*cumsum(delta)) * carry[n] * C[l,n]
//            uniform early break when cumsum(delta) > 183 (exp2 underflow,
//            valid because max_n A[d,n] = -0.5 by construction).
// CHUNK is a template param: 32 if workspace fits (13.7 MB), else 64.

#define BATCH 4
#define SEQ   2048
#define DDIM  768
#define NST   16
#define ROWS  (BATCH * SEQ)      // 8192
#define DT    (DDIM / 128)       // 6 d-tiles of 128
#define NOUT  33                 // 16 B + 16 C + 1 delta
#define LOG2E 1.4426950408889634f

__device__ __forceinline__ float fexp2(float x) {
#if __has_builtin(__builtin_amdgcn_exp2f)
  return __builtin_amdgcn_exp2f(x);
#else
  return exp2f(x);
#endif
}

// ---------------------------------------------------------------- k_proj ----
// Grid 256 blocks x 256 threads. Block = 32 rows. Thread (row=tid&31,
// ks=tid>>5) accumulates K slice [kt*96 + ks*12, +12) per tile kt=0..7.
__global__ __launch_bounds__(256) void k_proj(
    const float* __restrict__ u, const float* __restrict__ W_B,
    const float* __restrict__ W_C, const float* __restrict__ q_delta,
    const float* __restrict__ p_delta, float* __restrict__ delta,
    float* __restrict__ Bm, float* __restrict__ Cm) {
  __shared__ float Ws[NOUT * 96];      // 12.7 KB: W slice for current K tile
  __shared__ float Ps[4][32][NOUT];    // 16.9 KB: cross-wave partials

  const int tid  = threadIdx.x;
  const int rloc = tid & 31;
  const int ks   = tid >> 5;           // 0..7 K-split
  const int row  = blockIdx.x * 32 + rloc;

  float acc[NOUT];
#pragma unroll
  for (int j = 0; j < NOUT; ++j) acc[j] = 0.0f;

  const float* up0 = u + (size_t)row * DDIM + ks * 12;

  for (int kt = 0; kt < 8; ++kt) {
    // stage W[:, kt*96 .. kt*96+96) -> Ws[33][96]
    for (int f4 = tid; f4 < NOUT * 24; f4 += 256) {
      const int j   = f4 / 24;
      const int rem = f4 - j * 24;
      const float* base = (j < 16) ? (W_B + j * DDIM)
                        : (j < 32) ? (W_C + (j - 16) * DDIM)
                                   : q_delta;
      ((float4*)Ws)[f4] = ((const float4*)(base + kt * 96))[rem];
    }
    __syncthreads();

    const float* up = up0 + kt * 96;
    const float4 a0 = *(const float4*)(up + 0);
    const float4 a1 = *(const float4*)(up + 4);
    const float4 a2 = *(const float4*)(up + 8);
#pragma unroll
    for (int j = 0; j < NOUT; ++j) {
      const float4* wp = (const float4*)(Ws + j * 96 + ks * 12);
      const float4 w0 = wp[0], w1 = wp[1], w2 = wp[2];
      float s = acc[j];
      s = fmaf(a0.x, w0.x, s); s = fmaf(a0.y, w0.y, s);
      s = fmaf(a0.z, w0.z, s); s = fmaf(a0.w, w0.w, s);
      s = fmaf(a1.x, w1.x, s); s = fmaf(a1.y, w1.y, s);
      s = fmaf(a1.z, w1.z, s); s = fmaf(a1.w, w1.w, s);
      s = fmaf(a2.x, w2.x, s); s = fmaf(a2.y, w2.y, s);
      s = fmaf(a2.z, w2.z, s); s = fmaf(a2.w, w2.w, s);
      acc[j] = s;
    }
    __syncthreads();   // WAR: done reading Ws before next stage
  }

  // reduce 8 K-splits: ks pairs within wave via shfl, then 4 waves via LDS
  const int wave = tid >> 6, lane = tid & 63;
#pragma unroll
  for (int j = 0; j < NOUT; ++j) acc[j] += __shfl_xor(acc[j], 32);
  if (lane < 32) {
#pragma unroll
    for (int j = 0; j < NOUT; ++j) Ps[wave][lane][j] = acc[j];
  }
  __syncthreads();

  for (int f = tid; f < 32 * NOUT; f += 256) {
    const int r = f / NOUT, j = f - r * NOUT;
    const float s =
        Ps[0][r][j] + Ps[1][r][j] + Ps[2][r][j] + Ps[3][r][j];
    const int grow = blockIdx.x * 32 + r;
    if (j < 16) {
      Bm[grow * NST + j] = s;
    } else if (j < 32) {
      Cm[grow * NST + (j - 16)] = s;
    } else {
      const float z  = p_delta[0] + s;
      delta[grow] = fmaxf(z, 0.0f) + log1pf(expf(-fabsf(z)));
    }
  }
}

// ---------------------------------------------------------------- k_scan ----
// Block = 128 threads = one d-tile of one (b, chunk). Thread owns d, 16 states.
template <int CHUNK>
__global__ __launch_bounds__(128) void k_scan(
    const float* __restrict__ u, const float* __restrict__ A,
    const float* __restrict__ delta, const float* __restrict__ Bm,
    const float* __restrict__ Cm, float* __restrict__ y,
    float* __restrict__ xend) {
  constexpr int NC = SEQ / CHUNK;
  __shared__ float sdelta[CHUNK];
  __shared__ float Bs[CHUNK * NST];
  __shared__ float Cs[CHUNK * NST];

  const int dt = blockIdx.x % DT;
  const int c  = (blockIdx.x / DT) % NC;
  const int b  = blockIdx.x / (DT * NC);
  const int d  = dt * 128 + threadIdx.x;
  const int r0 = b * SEQ + c * CHUNK;

  for (int i = threadIdx.x; i < CHUNK * NST; i += 128) {
    Bs[i] = Bm[r0 * NST + i];
    Cs[i] = Cm[r0 * NST + i];
  }
  if (threadIdx.x < CHUNK) sdelta[threadIdx.x] = delta[r0 + threadIdx.x];
  __syncthreads();

  float A2[NST];
  {
    const float4* ap = (const float4*)(A + d * NST);
#pragma unroll
    for (int q = 0; q < 4; ++q) {
      const float4 t = ap[q];
      A2[4 * q + 0] = t.x * LOG2E; A2[4 * q + 1] = t.y * LOG2E;
      A2[4 * q + 2] = t.z * LOG2E; A2[4 * q + 3] = t.w * LOG2E;
    }
  }
  float x[NST];
#pragma unroll
  for (int n = 0; n < NST; ++n) x[n] = 0.0f;

  const float* up = u + (size_t)r0 * DDIM + d;
  float*       yp = y + (size_t)r0 * DDIM + d;

  for (int i = 0; i < CHUNK; ++i) {
    const float dl = sdelta[i];
    const float du = dl * up[i * DDIM];

    float bv[NST], cv[NST];
    {
      const float4* Bp = (const float4*)(Bs + i * NST);
      const float4* Cp = (const float4*)(Cs + i * NST);
#pragma unroll
      for (int q = 0; q < 4; ++q) {
        const float4 tb = Bp[q];
        bv[4 * q + 0] = tb.x; bv[4 * q + 1] = tb.y;
        bv[4 * q + 2] = tb.z; bv[4 * q + 3] = tb.w;
        const float4 tc = Cp[q];
        cv[4 * q + 0] = tc.x; cv[4 * q + 1] = tc.y;
        cv[4 * q + 2] = tc.z; cv[4 * q + 3] = tc.w;
      }
    }

    float acc[4] = {0.0f, 0.0f, 0.0f, 0.0f};
#pragma unroll
    for (int n = 0; n < NST; ++n) {
      const float dA = fexp2(A2[n] * dl);
      x[n] = fmaf(dA, x[n], du * bv[n]);
      acc[n & 3] = fmaf(x[n], cv[n], acc[n & 3]);
    }
    yp[i * DDIM] = (acc[0] + acc[1]) + (acc[2] + acc[3]);
  }

  float4* xe = (float4*)(xend + ((size_t)((b * NC + c) * DDIM + d)) * NST);
  xe[0] = make_float4(x[0], x[1], x[2], x[3]);
  xe[1] = make_float4(x[4], x[5], x[6], x[7]);
  xe[2] = make_float4(x[8], x[9], x[10], x[11]);
  xe[3] = make_float4(x[12], x[13], x[14], x[15]);
}

// --------------------------------------------------------------- k_carry ----
// Block = 256 threads = (16 d) x (16 n) for one batch's 16-d block. Sequential
// over NC chunks. Rewrites xend[c] with the carry ENTERING chunk c.
template <int CHUNK>
__global__ __launch_bounds__(256) void k_carry(
    const float* __restrict__ A, const float* __restrict__ delta,
    float* __restrict__ xend) {
  constexpr int NC  = SEQ / CHUNK;
  constexpr int TPC = CHUNK / 8;       // threads per chunk-sum
  __shared__ float Ds[NC];
  const int b    = blockIdx.x / (DDIM / 16);
  const int dblk = blockIdx.x % (DDIM / 16);
  const int tid  = threadIdx.x;

  {
    float s = 0.0f;
    const float* dp = delta + b * SEQ + tid * 8;
#pragma unroll
    for (int k = 0; k < 8; ++k) s += dp[k];
#pragma unroll
    for (int off = 1; off < TPC; off <<= 1) s += __shfl_xor(s, off);
    if ((tid & (TPC - 1)) == 0) Ds[tid / TPC] = s;
  }
  __syncthreads();

  const int n = tid & 15;
  const int d = dblk * 16 + (tid >> 4);
  const float A2 = A[d * NST + n] * LOG2E;

  float carry = 0.0f;
  for (int c = 0; c < NC; ++c) {
    const size_t idx = ((size_t)((b * NC + c) * DDIM + d)) * NST + n;
    const float xe = xend[idx];
    const float P  = fexp2(A2 * Ds[c]);
    xend[idx] = carry;               // carry entering chunk c
    carry = fmaf(P, carry, xe);
  }
}

// ----------------------------------------------------------------- k_fix ----
// Adds carry-in correction to y for chunks 1..NC-1. Uniform early break when
// cumulative delta > 183 (exp2 argument < -132 for every A <= -0.5).
template <int CHUNK>
__global__ __launch_bounds__(128) void k_fix(
    const float* __restrict__ A, const float* __restrict__ delta,
    const float* __restrict__ Cm, const float* __restrict__ xend,
    float* __restrict__ y) {
  constexpr int NC = SEQ / CHUNK;
  const int dt = blockIdx.x % DT;
  const int c  = (blockIdx.x / DT) % (NC - 1) + 1;
  const int b  = blockIdx.x / (DT * (NC - 1));
  const int d  = dt * 128 + threadIdx.x;

  float A2[NST], carry[NST];
  {
    const float4* ap = (const float4*)(A + d * NST);
#pragma unroll
    for (int q = 0; q < 4; ++q) {
      const float4 t = ap[q];
      A2[4 * q + 0] = t.x * LOG2E; A2[4 * q + 1] = t.y * LOG2E;
      A2[4 * q + 2] = t.z * LOG2E; A2[4 * q + 3] = t.w * LOG2E;
    }
    const float4* cp =
        (const float4*)(xend + ((size_t)((b * NC + c) * DDIM + d)) * NST);
#pragma unroll
    for (int q = 0; q < 4; ++q) {
      const float4 t = cp[q];
      carry[4 * q + 0] = t.x; carry[4 * q + 1] = t.y;
      carry[4 * q + 2] = t.z; carry[4 * q + 3] = t.w;
    }
  }

  const int r0 = b * SEQ + c * CHUNK;
  float* yp = y + (size_t)r0 * DDIM + d;

  float dS = 0.0f;
  for (int i = 0; i < CHUNK; ++i) {
    dS += delta[r0 + i];
    if (dS > 183.0f) break;   // uniform across block (delta shared)
    float cv[NST];
    {
      const float4* Cp = (const float4*)(Cm + (size_t)(r0 + i) * NST);
#pragma unroll
      for (int q = 0; q < 4; ++q) {
        const float4 t = Cp[q];
        cv[4 * q + 0] = t.x; cv[4 * q + 1] = t.y;
        cv[4 * q + 2] = t.z; cv[4 * q + 3] = t.w;
      }
    }
    float acc[4] = {0.0f, 0.0f, 0.0f, 0.0f};
#pragma unroll
    for (int n = 0; n < NST; ++n) {
      const float e = fexp2(A2[n] * dS);
      acc[n & 3] = fmaf(e * carry[n], cv[n], acc[n & 3]);
    }
    yp[i * DDIM] += (acc[0] + acc[1]) + (acc[2] + acc[3]);
  }
}

// ------------------------------------------------------------------ launch --
template <int CHUNK>
static void launch_pipeline(const float* u, const float* A, const float* W_B,
                            const float* W_C, const float* q_delta,
                            const float* p_delta, float* y, float* ws,
                            hipStream_t stream) {
  constexpr int NC = SEQ / CHUNK;
  float* delta = ws;                         // ROWS
  float* Bm    = delta + ROWS;               // ROWS*NST
  float* Cm    = Bm + (size_t)ROWS * NST;    // ROWS*NST
  float* xend  = Cm + (size_t)ROWS * NST;    // BATCH*NC*DDIM*NST

  hipLaunchKernelGGL(k_proj, dim3(ROWS / 32), dim3(256), 0, stream,
                     u, W_B, W_C, q_delta, p_delta, delta, Bm, Cm);
  hipLaunchKernelGGL((k_scan<CHUNK>), dim3(BATCH * NC * DT), dim3(128), 0,
                     stream, u, A, delta, Bm, Cm, y, xend);
  hipLaunchKernelGGL((k_carry<CHUNK>), dim3(BATCH * (DDIM / 16)), dim3(256), 0,
                     stream, A, delta, xend);
  hipLaunchKernelGGL((k_fix<CHUNK>), dim3(BATCH * (NC - 1) * DT), dim3(128), 0,
                     stream, A, delta, Cm, xend, y);
}

extern "C" void kernel_launch(void* const* d_in, const int* in_sizes, int n_in,
                              void* d_out, int out_size, void* d_ws,
                              size_t ws_size, hipStream_t stream) {
  const float* u       = (const float*)d_in[0];
  const float* A       = (const float*)d_in[1];
  const float* W_B     = (const float*)d_in[2];
  const float* W_C     = (const float*)d_in[3];
  const float* q_delta = (const float*)d_in[4];
  const float* p_delta = (const float*)d_in[5];
  float* y  = (float*)d_out;
  float* ws = (float*)d_ws;

  const size_t need32 =
      ((size_t)ROWS + 2 * (size_t)ROWS * NST +
       (size_t)BATCH * (SEQ / 32) * DDIM * NST) * sizeof(float);
  if (ws_size >= need32) {
    launch_pipeline<32>(u, A, W_B, W_C, q_delta, p_delta, y, ws, stream);
  } else {
    launch_pipeline<64>(u, A, W_B, W_C, q_delta, p_delta, y, ws, stream);
  }
}

// Round 3
// 145.687 us; speedup vs baseline: 1.6906x; 1.2493x over previous
//
#include <hip/hip_runtime.h>
#include <math.h>

// Selective SSM (Mamba-style) chunked-scan, round 3.
// Shapes: BATCH=4, SEQ=2048, D=768, N=16.  CHUNK=64 fixed (NC=32).
//   k_proj : delta/B/C projections. 512 blocks x 16 rows, K-tile 128 in LDS,
//            16 K-splits of 8 per row; shfl+LDS reduce. 2 blocks/CU.
//   k_scan : thread pair owns (d, 8-of-16 states); 3 waves/SIMD. Local scan
//            x0=0, y via shfl_xor(1), writes chunk-end state.
//   k_carry: per (b,d,n): carry_{c+1} = exp2(A2*Dsum_c)*carry_c + xend_c.
//   k_fix  : y += sum_n exp2(A2[n]*cumsum(delta))*carry[n]*C[l,n]; uniform
//            break at cumsum > 64 (exp2 arg < -46 for all A <= -0.5:
//            contribution < 1e-5, threshold is 4.5e4).

#define BATCH 4
#define SEQ   2048
#define DDIM  768
#define NST   16
#define CHUNK 64
#define NC    (SEQ / CHUNK)      // 32
#define ROWS  (BATCH * SEQ)      // 8192
#define DT    (DDIM / 128)       // 6
#define NOUT  33
#define LOG2E 1.4426950408889634f
#define FIX_THR 64.0f

__device__ __forceinline__ float fexp2(float x) {
#if __has_builtin(__builtin_amdgcn_exp2f)
  return __builtin_amdgcn_exp2f(x);
#else
  return exp2f(x);
#endif
}

// ---------------------------------------------------------------- k_proj ----
// 512 blocks x 256 thr. Block = 16 rows; thread (rloc=tid&15, ks=tid>>4).
// K tiled 6 x 128; W slice in LDS (broadcast b128 reads); u as float4.
__global__ __launch_bounds__(256) void k_proj(
    const float* __restrict__ u, const float* __restrict__ W_B,
    const float* __restrict__ W_C, const float* __restrict__ q_delta,
    const float* __restrict__ p_delta, float* __restrict__ delta,
    float* __restrict__ Bm, float* __restrict__ Cm) {
  __shared__ float Ws[NOUT * 128];       // 16.9 KB
  __shared__ float Ps[4][16][NOUT];      // 8.4 KB

  const int tid  = threadIdx.x;
  const int rloc = tid & 15;
  const int ks   = tid >> 4;             // 0..15, K-split of 8
  const int row  = blockIdx.x * 16 + rloc;

  float acc[NOUT];
#pragma unroll
  for (int j = 0; j < NOUT; ++j) acc[j] = 0.0f;

  const float* up0 = u + (size_t)row * DDIM + ks * 8;

  for (int kt = 0; kt < 6; ++kt) {
    for (int f4 = tid; f4 < NOUT * 32; f4 += 256) {
      const int j   = f4 >> 5;
      const int rem = f4 & 31;
      const float* base = (j < 16) ? (W_B + j * DDIM)
                        : (j < 32) ? (W_C + (j - 16) * DDIM)
                                   : q_delta;
      ((float4*)Ws)[f4] = ((const float4*)(base + kt * 128))[rem];
    }
    __syncthreads();

    const float* up = up0 + kt * 128;
    const float4 a0 = ((const float4*)up)[0];
    const float4 a1 = ((const float4*)up)[1];
#pragma unroll
    for (int j = 0; j < NOUT; ++j) {
      const float4* wp = (const float4*)(Ws + j * 128 + ks * 8);
      const float4 w0 = wp[0], w1 = wp[1];
      float s = acc[j];
      s = fmaf(a0.x, w0.x, s); s = fmaf(a0.y, w0.y, s);
      s = fmaf(a0.z, w0.z, s); s = fmaf(a0.w, w0.w, s);
      s = fmaf(a1.x, w1.x, s); s = fmaf(a1.y, w1.y, s);
      s = fmaf(a1.z, w1.z, s); s = fmaf(a1.w, w1.w, s);
      acc[j] = s;
    }
    __syncthreads();
  }

  // reduce ks: shfl_xor(16),(32) sums the 4 ks values within each wave,
  // then 4 waves combine through LDS.
  const int wave = tid >> 6;
#pragma unroll
  for (int j = 0; j < NOUT; ++j) {
    acc[j] += __shfl_xor(acc[j], 16);
    acc[j] += __shfl_xor(acc[j], 32);
  }
  if ((tid & 48) == 0) {                 // one lane per (wave, rloc)
#pragma unroll
    for (int j = 0; j < NOUT; ++j) Ps[wave][rloc][j] = acc[j];
  }
  __syncthreads();

  for (int f = tid; f < 16 * NOUT; f += 256) {
    const int r = f / NOUT, j = f - r * NOUT;
    const float s = Ps[0][r][j] + Ps[1][r][j] + Ps[2][r][j] + Ps[3][r][j];
    const int grow = blockIdx.x * 16 + r;
    if (j < 16) {
      Bm[grow * NST + j] = s;
    } else if (j < 32) {
      Cm[grow * NST + (j - 16)] = s;
    } else {
      const float z = p_delta[0] + s;
      delta[grow] = fmaxf(z, 0.0f) + log1pf(expf(-fabsf(z)));
    }
  }
}

// ---------------------------------------------------------------- k_scan ----
// 768 blocks x 256 thr. Thread (h=tid&1, dl=tid>>1) owns (d, states h*8..+8).
__global__ __launch_bounds__(256) void k_scan(
    const float* __restrict__ u, const float* __restrict__ A,
    const float* __restrict__ delta, const float* __restrict__ Bm,
    const float* __restrict__ Cm, float* __restrict__ y,
    float* __restrict__ xend) {
  __shared__ float sdelta[CHUNK];
  __shared__ float Bs[CHUNK * NST];
  __shared__ float Cs[CHUNK * NST];

  const int dt  = blockIdx.x % DT;
  const int c   = (blockIdx.x / DT) % NC;
  const int b   = blockIdx.x / (DT * NC);
  const int tid = threadIdx.x;
  const int h   = tid & 1;
  const int dl  = tid >> 1;
  const int d   = dt * 128 + dl;
  const int r0  = b * SEQ + c * CHUNK;

  for (int i = tid; i < CHUNK * NST; i += 256) {
    Bs[i] = Bm[r0 * NST + i];
    Cs[i] = Cm[r0 * NST + i];
  }
  if (tid < CHUNK) sdelta[tid] = delta[r0 + tid];
  __syncthreads();

  float A2[8];
  {
    const float4* ap = (const float4*)(A + d * NST + h * 8);
    const float4 t0 = ap[0], t1 = ap[1];
    A2[0] = t0.x * LOG2E; A2[1] = t0.y * LOG2E;
    A2[2] = t0.z * LOG2E; A2[3] = t0.w * LOG2E;
    A2[4] = t1.x * LOG2E; A2[5] = t1.y * LOG2E;
    A2[6] = t1.z * LOG2E; A2[7] = t1.w * LOG2E;
  }
  float x[8];
#pragma unroll
  for (int n = 0; n < 8; ++n) x[n] = 0.0f;

  const float* up = u + (size_t)r0 * DDIM + d;
  float*       yp = y + (size_t)r0 * DDIM + d;

  for (int i = 0; i < CHUNK; ++i) {
    const float dlt = sdelta[i];
    const float du  = dlt * up[(size_t)i * DDIM];

    const float4* Bp = (const float4*)(Bs + i * NST + h * 8);
    const float4* Cp = (const float4*)(Cs + i * NST + h * 8);
    const float4 b0 = Bp[0], b1 = Bp[1];
    const float4 c0 = Cp[0], c1 = Cp[1];
    const float bv[8] = {b0.x, b0.y, b0.z, b0.w, b1.x, b1.y, b1.z, b1.w};
    const float cv[8] = {c0.x, c0.y, c0.z, c0.w, c1.x, c1.y, c1.z, c1.w};

    float a0 = 0.0f, a1 = 0.0f;
#pragma unroll
    for (int n = 0; n < 8; ++n) {
      const float e = fexp2(A2[n] * dlt);
      x[n] = fmaf(e, x[n], du * bv[n]);
      if (n < 4) a0 = fmaf(x[n], cv[n], a0);
      else       a1 = fmaf(x[n], cv[n], a1);
    }
    float ys = a0 + a1;
    ys += __shfl_xor(ys, 1);
    if (h == 0) yp[(size_t)i * DDIM] = ys;
  }

  float4* xe =
      (float4*)(xend + ((size_t)((b * NC + c) * DDIM + d)) * NST + h * 8);
  xe[0] = make_float4(x[0], x[1], x[2], x[3]);
  xe[1] = make_float4(x[4], x[5], x[6], x[7]);
}

// --------------------------------------------------------------- k_carry ----
// 192 blocks x 256 thr = (16 d) x (16 n) per block. Sequential over 32 chunks.
// Rewrites xend[c] with the carry ENTERING chunk c.
__global__ __launch_bounds__(256) void k_carry(
    const float* __restrict__ A, const float* __restrict__ delta,
    float* __restrict__ xend) {
  __shared__ float Ds[NC];
  const int b    = blockIdx.x / (DDIM / 16);
  const int dblk = blockIdx.x % (DDIM / 16);
  const int tid  = threadIdx.x;

  {
    float s = 0.0f;
    const float* dp = delta + b * SEQ + tid * 8;
#pragma unroll
    for (int k = 0; k < 8; ++k) s += dp[k];
    s += __shfl_xor(s, 1);
    s += __shfl_xor(s, 2);
    s += __shfl_xor(s, 4);
    if ((tid & 7) == 0) Ds[tid >> 3] = s;   // 8 threads per chunk of 64
  }
  __syncthreads();

  const int n = tid & 15;
  const int d = dblk * 16 + (tid >> 4);
  const float A2 = A[d * NST + n] * LOG2E;

  float carry = 0.0f;
  for (int c = 0; c < NC; ++c) {
    const size_t idx = ((size_t)((b * NC + c) * DDIM + d)) * NST + n;
    const float xe = xend[idx];
    const float P  = fexp2(A2 * Ds[c]);
    xend[idx] = carry;
    carry = fmaf(P, carry, xe);
  }
}

// ----------------------------------------------------------------- k_fix ----
// 744 blocks x 256 thr; thread (h, dl) as in k_scan. Chunks 1..NC-1.
__global__ __launch_bounds__(256) void k_fix(
    const float* __restrict__ A, const float* __restrict__ delta,
    const float* __restrict__ Cm, const float* __restrict__ xend,
    float* __restrict__ y) {
  __shared__ float sdelta[CHUNK];
  const int dt  = blockIdx.x % DT;
  const int c   = (blockIdx.x / DT) % (NC - 1) + 1;
  const int b   = blockIdx.x / (DT * (NC - 1));
  const int tid = threadIdx.x;
  const int h   = tid & 1;
  const int dl  = tid >> 1;
  const int d   = dt * 128 + dl;
  const int r0  = b * SEQ + c * CHUNK;

  if (tid < CHUNK) sdelta[tid] = delta[r0 + tid];
  __syncthreads();

  float A2[8], carry[8];
  {
    const float4* ap = (const float4*)(A + d * NST + h * 8);
    const float4 t0 = ap[0], t1 = ap[1];
    A2[0] = t0.x * LOG2E; A2[1] = t0.y * LOG2E;
    A2[2] = t0.z * LOG2E; A2[3] = t0.w * LOG2E;
    A2[4] = t1.x * LOG2E; A2[5] = t1.y * LOG2E;
    A2[6] = t1.z * LOG2E; A2[7] = t1.w * LOG2E;
    const float4* cp = (const float4*)(
        xend + ((size_t)((b * NC + c) * DDIM + d)) * NST + h * 8);
    const float4 q0 = cp[0], q1 = cp[1];
    carry[0] = q0.x; carry[1] = q0.y; carry[2] = q0.z; carry[3] = q0.w;
    carry[4] = q1.x; carry[5] = q1.y; carry[6] = q1.z; carry[7] = q1.w;
  }

  const float* Cp0 = Cm + (size_t)r0 * NST + h * 8;
  float* yp = y + (size_t)r0 * DDIM + d;

  float dS = 0.0f;
  for (int i = 0; i < CHUNK; ++i) {
    dS += sdelta[i];
    if (dS > FIX_THR) break;             // uniform across block
    const float4* Cp = (const float4*)(Cp0 + i * NST);
    const float4 c0 = Cp[0], c1 = Cp[1];
    const float cv[8] = {c0.x, c0.y, c0.z, c0.w, c1.x, c1.y, c1.z, c1.w};
    float a0 = 0.0f, a1 = 0.0f;
#pragma unroll
    for (int n = 0; n < 8; ++n) {
      const float e = fexp2(A2[n] * dS);
      if (n < 4) a0 = fmaf(e * carry[n], cv[n], a0);
      else       a1 = fmaf(e * carry[n], cv[n], a1);
    }
    float ys = a0 + a1;
    ys += __shfl_xor(ys, 1);
    if (h == 0) yp[(size_t)i * DDIM] += ys;
  }
}

// ------------------------------------------------------------------ launch --
extern "C" void kernel_launch(void* const* d_in, const int* in_sizes, int n_in,
                              void* d_out, int out_size, void* d_ws,
                              size_t ws_size, hipStream_t stream) {
  const float* u       = (const float*)d_in[0];
  const float* A       = (const float*)d_in[1];
  const float* W_B     = (const float*)d_in[2];
  const float* W_C     = (const float*)d_in[3];
  const float* q_delta = (const float*)d_in[4];
  const float* p_delta = (const float*)d_in[5];
  float* y  = (float*)d_out;
  float* ws = (float*)d_ws;

  float* delta = ws;                 // 8192
  float* Bm    = ws + 8192;          // 131072
  float* Cm    = ws + 139264;        // 131072
  float* xend  = ws + 270336;        // 1572864   (total 7.37 MB)

  hipLaunchKernelGGL(k_proj, dim3(ROWS / 16), dim3(256), 0, stream,
                     u, W_B, W_C, q_delta, p_delta, delta, Bm, Cm);
  hipLaunchKernelGGL(k_scan, dim3(BATCH * NC * DT), dim3(256), 0, stream,
                     u, A, delta, Bm, Cm, y, xend);
  hipLaunchKernelGGL(k_carry, dim3(BATCH * (DDIM / 16)), dim3(256), 0, stream,
                     A, delta, xend);
  hipLaunchKernelGGL(k_fix, dim3(BATCH * (NC - 1) * DT), dim3(256), 0, stream,
                     A, delta, Cm, xend, y);
}

// Round 4
// 141.060 us; speedup vs baseline: 1.7460x; 1.0328x over previous
//
#include <hip/hip_runtime.h>
#include <math.h>

// Selective SSM (Mamba-style) chunked-scan, round 4.
// Shapes: BATCH=4, SEQ=2048, D=768, N=16.  CHUNK=64 (NC=32).
//   k_proj : delta/B/C projections. Block = 8 rows, 256 thr = (jg 0..7) x
//            (ks 0..31). Thread owns J=4 output rows of W in REGISTERS
//            (jg0 also owns q_delta), u tile double-buffered in LDS and
//            broadcast-read -> LDS traffic / 4 vs round 3; FMA-bound.
//            K-reduce via 5-level shfl_xor within 32-lane groups.
//   k_scan : thread pair owns (d, 8-of-16 states); u prefetched 1 step ahead.
//            Local scan x0=0, y via shfl_xor(1), writes chunk-end state.
//   k_fix  : fused carry + correction. Carry entering chunk c computed by
//            walk-back: carry += factor * xend[cb]; factor *= exp2(A2*Ds_cb);
//            uniform break when cum chunk-delta > 64 (exp2 arg < -46 for all
//            A <= -0.5 => contribution < 1e-9; threshold is 4.5e4). In
//            practice Ds ~ 700 so exactly one term (xend[c-1]) survives.
//            Then y += sum_n exp2(A2[n]*cumsum(delta))*carry[n]*C[l,n] with
//            the same uniform cutoff. (k_carry kernel eliminated.)

#define BATCH 4
#define SEQ   2048
#define DDIM  768
#define NST   16
#define CHUNK 64
#define NC    (SEQ / CHUNK)      // 32
#define ROWS  (BATCH * SEQ)      // 8192
#define DT    (DDIM / 128)       // 6
#define LOG2E 1.4426950408889634f
#define FIX_THR 64.0f

__device__ __forceinline__ float fexp2(float x) {
#if __has_builtin(__builtin_amdgcn_exp2f)
  return __builtin_amdgcn_exp2f(x);
#else
  return exp2f(x);
#endif
}

// ---------------------------------------------------------------- k_proj ----
// 1024 blocks x 256 thr. Block = 8 rows. Thread (jg=tid>>5, ks=tid&31) owns
// output js {4jg..4jg+3} (+ q_delta for jg==0) and K-slice ks*4..+4 per tile.
__global__ __launch_bounds__(256) void k_proj(
    const float* __restrict__ u, const float* __restrict__ W_B,
    const float* __restrict__ W_C, const float* __restrict__ q_delta,
    const float* __restrict__ p_delta, float* __restrict__ delta,
    float* __restrict__ Bm, float* __restrict__ Cm) {
  __shared__ float u_s[2][8 * 128];     // 8 KB double-buffered u tile

  const int tid = threadIdx.x;
  const int jg  = tid >> 5;             // 0..7
  const int ks  = tid & 31;             // 0..31
  const int r0  = blockIdx.x * 8;

  const float* wrow[4];
#pragma unroll
  for (int jj = 0; jj < 4; ++jj) {
    const int j = jg * 4 + jj;
    wrow[jj] = (j < 16) ? (W_B + (size_t)j * DDIM)
                        : (W_C + (size_t)(j - 16) * DDIM);
  }

  const float* ubase = u + (size_t)r0 * DDIM;
  // prologue: stage tile 0 (thread tid covers row tid>>5, float4 col tid&31)
  ((float4*)u_s[0])[tid] =
      *(const float4*)(ubase + (size_t)(tid >> 5) * DDIM + (tid & 31) * 4);

  float acc[4][8];
#pragma unroll
  for (int jj = 0; jj < 4; ++jj)
#pragma unroll
    for (int r = 0; r < 8; ++r) acc[jj][r] = 0.0f;
  float accd[8];
#pragma unroll
  for (int r = 0; r < 8; ++r) accd[r] = 0.0f;

  for (int kt = 0; kt < 6; ++kt) {
    __syncthreads();                    // u_s[kt&1] ready
    float4 nxt;
    if (kt < 5)
      nxt = *(const float4*)(ubase + (size_t)(tid >> 5) * DDIM +
                             (kt + 1) * 128 + (tid & 31) * 4);
    float4 w[4];
#pragma unroll
    for (int jj = 0; jj < 4; ++jj)
      w[jj] = *(const float4*)(wrow[jj] + kt * 128 + ks * 4);
    float4 qd = make_float4(0.f, 0.f, 0.f, 0.f);
    if (jg == 0) qd = *(const float4*)(q_delta + kt * 128 + ks * 4);

    const float4* us = (const float4*)u_s[kt & 1];
#pragma unroll
    for (int r = 0; r < 8; ++r) {
      const float4 uv = us[r * 32 + ks];
#pragma unroll
      for (int jj = 0; jj < 4; ++jj) {
        float s = acc[jj][r];
        s = fmaf(uv.x, w[jj].x, s); s = fmaf(uv.y, w[jj].y, s);
        s = fmaf(uv.z, w[jj].z, s); s = fmaf(uv.w, w[jj].w, s);
        acc[jj][r] = s;
      }
      if (jg == 0) {
        float s = accd[r];
        s = fmaf(uv.x, qd.x, s); s = fmaf(uv.y, qd.y, s);
        s = fmaf(uv.z, qd.z, s); s = fmaf(uv.w, qd.w, s);
        accd[r] = s;
      }
    }
    if (kt < 5) ((float4*)u_s[(kt + 1) & 1])[tid] = nxt;
  }

  // reduce across the 32 ks lanes (stays within 32-lane halves of the wave)
#pragma unroll
  for (int jj = 0; jj < 4; ++jj)
#pragma unroll
    for (int r = 0; r < 8; ++r) {
      float s = acc[jj][r];
      s += __shfl_xor(s, 1);  s += __shfl_xor(s, 2);
      s += __shfl_xor(s, 4);  s += __shfl_xor(s, 8);
      s += __shfl_xor(s, 16);
      acc[jj][r] = s;
    }
  if (jg == 0) {
#pragma unroll
    for (int r = 0; r < 8; ++r) {
      float s = accd[r];
      s += __shfl_xor(s, 1);  s += __shfl_xor(s, 2);
      s += __shfl_xor(s, 4);  s += __shfl_xor(s, 8);
      s += __shfl_xor(s, 16);
      accd[r] = s;
    }
  }

  if (ks == 0) {
#pragma unroll
    for (int jj = 0; jj < 4; ++jj) {
      const int j = jg * 4 + jj;
#pragma unroll
      for (int r = 0; r < 8; ++r) {
        const int row = r0 + r;
        if (j < 16) Bm[row * NST + j] = acc[jj][r];
        else        Cm[row * NST + (j - 16)] = acc[jj][r];
      }
    }
    if (jg == 0) {
      const float p = p_delta[0];
#pragma unroll
      for (int r = 0; r < 8; ++r) {
        const float z = p + accd[r];
        delta[r0 + r] = fmaxf(z, 0.0f) + log1pf(expf(-fabsf(z)));
      }
    }
  }
}

// ---------------------------------------------------------------- k_scan ----
// 768 blocks x 256 thr. Thread (h=tid&1, dl=tid>>1) owns (d, states h*8..+8).
__global__ __launch_bounds__(256) void k_scan(
    const float* __restrict__ u, const float* __restrict__ A,
    const float* __restrict__ delta, const float* __restrict__ Bm,
    const float* __restrict__ Cm, float* __restrict__ y,
    float* __restrict__ xend) {
  __shared__ float sdelta[CHUNK];
  __shared__ float Bs[CHUNK * NST];
  __shared__ float Cs[CHUNK * NST];

  const int dt  = blockIdx.x % DT;
  const int c   = (blockIdx.x / DT) % NC;
  const int b   = blockIdx.x / (DT * NC);
  const int tid = threadIdx.x;
  const int h   = tid & 1;
  const int dl  = tid >> 1;
  const int d   = dt * 128 + dl;
  const int r0  = b * SEQ + c * CHUNK;

  for (int i = tid; i < CHUNK * NST; i += 256) {
    Bs[i] = Bm[r0 * NST + i];
    Cs[i] = Cm[r0 * NST + i];
  }
  if (tid < CHUNK) sdelta[tid] = delta[r0 + tid];
  __syncthreads();

  float A2[8];
  {
    const float4* ap = (const float4*)(A + d * NST + h * 8);
    const float4 t0 = ap[0], t1 = ap[1];
    A2[0] = t0.x * LOG2E; A2[1] = t0.y * LOG2E;
    A2[2] = t0.z * LOG2E; A2[3] = t0.w * LOG2E;
    A2[4] = t1.x * LOG2E; A2[5] = t1.y * LOG2E;
    A2[6] = t1.z * LOG2E; A2[7] = t1.w * LOG2E;
  }
  float x[8];
#pragma unroll
  for (int n = 0; n < 8; ++n) x[n] = 0.0f;

  const float* up = u + (size_t)r0 * DDIM + d;
  float*       yp = y + (size_t)r0 * DDIM + d;

  float u_nxt = up[0];
  for (int i = 0; i < CHUNK; ++i) {
    const float u_cur = u_nxt;
    if (i + 1 < CHUNK) u_nxt = up[(size_t)(i + 1) * DDIM];

    const float dlt = sdelta[i];
    const float du  = dlt * u_cur;

    const float4* Bp = (const float4*)(Bs + i * NST + h * 8);
    const float4* Cp = (const float4*)(Cs + i * NST + h * 8);
    const float4 b0 = Bp[0], b1 = Bp[1];
    const float4 c0 = Cp[0], c1 = Cp[1];
    const float bv[8] = {b0.x, b0.y, b0.z, b0.w, b1.x, b1.y, b1.z, b1.w};
    const float cv[8] = {c0.x, c0.y, c0.z, c0.w, c1.x, c1.y, c1.z, c1.w};

    float a0 = 0.0f, a1 = 0.0f;
#pragma unroll
    for (int n = 0; n < 8; ++n) {
      const float e = fexp2(A2[n] * dlt);
      x[n] = fmaf(e, x[n], du * bv[n]);
      if (n < 4) a0 = fmaf(x[n], cv[n], a0);
      else       a1 = fmaf(x[n], cv[n], a1);
    }
    float ys = a0 + a1;
    ys += __shfl_xor(ys, 1);
    if (h == 0) yp[(size_t)i * DDIM] = ys;
  }

  float4* xe =
      (float4*)(xend + ((size_t)((b * NC + c) * DDIM + d)) * NST + h * 8);
  xe[0] = make_float4(x[0], x[1], x[2], x[3]);
  xe[1] = make_float4(x[4], x[5], x[6], x[7]);
}

// ----------------------------------------------------------------- k_fix ----
// 744 blocks x 256 thr; thread (h, dl) as in k_scan. Chunks 1..NC-1.
// Fused carry walk-back + correction pass.
__global__ __launch_bounds__(256) void k_fix(
    const float* __restrict__ A, const float* __restrict__ delta,
    const float* __restrict__ Cm, const float* __restrict__ xend,
    float* __restrict__ y) {
  __shared__ float sdelta[CHUNK];
  __shared__ float sDs;
  const int dt  = blockIdx.x % DT;
  const int c   = (blockIdx.x / DT) % (NC - 1) + 1;
  const int b   = blockIdx.x / (DT * (NC - 1));
  const int tid = threadIdx.x;
  const int h   = tid & 1;
  const int dl  = tid >> 1;
  const int d   = dt * 128 + dl;
  const int r0  = b * SEQ + c * CHUNK;

  if (tid < CHUNK) sdelta[tid] = delta[r0 + tid];

  float A2[8];
  {
    const float4* ap = (const float4*)(A + d * NST + h * 8);
    const float4 t0 = ap[0], t1 = ap[1];
    A2[0] = t0.x * LOG2E; A2[1] = t0.y * LOG2E;
    A2[2] = t0.z * LOG2E; A2[3] = t0.w * LOG2E;
    A2[4] = t1.x * LOG2E; A2[5] = t1.y * LOG2E;
    A2[6] = t1.z * LOG2E; A2[7] = t1.w * LOG2E;
  }

  // ---- carry walk-back: carry = sum_j (prod P) * xend[c-j], early cutoff.
  float carry[8]  = {0.f, 0.f, 0.f, 0.f, 0.f, 0.f, 0.f, 0.f};
  float factor[8] = {1.f, 1.f, 1.f, 1.f, 1.f, 1.f, 1.f, 1.f};
  float cumD = 0.0f;
  for (int cb = c - 1; cb >= 0; --cb) {
    const float4* cp = (const float4*)(
        xend + ((size_t)((b * NC + cb) * DDIM + d)) * NST + h * 8);
    const float4 q0 = cp[0], q1 = cp[1];
    carry[0] = fmaf(factor[0], q0.x, carry[0]);
    carry[1] = fmaf(factor[1], q0.y, carry[1]);
    carry[2] = fmaf(factor[2], q0.z, carry[2]);
    carry[3] = fmaf(factor[3], q0.w, carry[3]);
    carry[4] = fmaf(factor[4], q1.x, carry[4]);
    carry[5] = fmaf(factor[5], q1.y, carry[5]);
    carry[6] = fmaf(factor[6], q1.z, carry[6]);
    carry[7] = fmaf(factor[7], q1.w, carry[7]);

    __syncthreads();
    if (tid < 64) {
      float v = delta[b * SEQ + cb * CHUNK + tid];
      v += __shfl_xor(v, 1);  v += __shfl_xor(v, 2);
      v += __shfl_xor(v, 4);  v += __shfl_xor(v, 8);
      v += __shfl_xor(v, 16); v += __shfl_xor(v, 32);
      if (tid == 0) sDs = v;
    }
    __syncthreads();
    const float Ds = sDs;
    cumD += Ds;
    if (cumD > FIX_THR) break;          // uniform across block
#pragma unroll
    for (int n = 0; n < 8; ++n) factor[n] *= fexp2(A2[n] * Ds);
  }
  // >=1 loop iteration always ran (c>=1), each with two barriers, so the
  // sdelta stores above are visible now.

  const float* Cp0 = Cm + (size_t)r0 * NST + h * 8;
  float* yp = y + (size_t)r0 * DDIM + d;

  float dS = 0.0f;
  for (int i = 0; i < CHUNK; ++i) {
    dS += sdelta[i];
    if (dS > FIX_THR) break;            // uniform across block
    const float4* Cp = (const float4*)(Cp0 + i * NST);
    const float4 c0 = Cp[0], c1 = Cp[1];
    const float cv[8] = {c0.x, c0.y, c0.z, c0.w, c1.x, c1.y, c1.z, c1.w};
    float a0 = 0.0f, a1 = 0.0f;
#pragma unroll
    for (int n = 0; n < 8; ++n) {
      const float e = fexp2(A2[n] * dS);
      if (n < 4) a0 = fmaf(e * carry[n], cv[n], a0);
      else       a1 = fmaf(e * carry[n], cv[n], a1);
    }
    float ys = a0 + a1;
    ys += __shfl_xor(ys, 1);
    if (h == 0) yp[(size_t)i * DDIM] += ys;
  }
}

// ------------------------------------------------------------------ launch --
extern "C" void kernel_launch(void* const* d_in, const int* in_sizes, int n_in,
                              void* d_out, int out_size, void* d_ws,
                              size_t ws_size, hipStream_t stream) {
  const float* u       = (const float*)d_in[0];
  const float* A       = (const float*)d_in[1];
  const float* W_B     = (const float*)d_in[2];
  const float* W_C     = (const float*)d_in[3];
  const float* q_delta = (const float*)d_in[4];
  const float* p_delta = (const float*)d_in[5];
  float* y  = (float*)d_out;
  float* ws = (float*)d_ws;

  float* delta = ws;                 // 8192
  float* Bm    = ws + 8192;          // 131072
  float* Cm    = ws + 139264;        // 131072
  float* xend  = ws + 270336;        // 1572864   (total 7.37 MB)

  hipLaunchKernelGGL(k_proj, dim3(ROWS / 8), dim3(256), 0, stream,
                     u, W_B, W_C, q_delta, p_delta, delta, Bm, Cm);
  hipLaunchKernelGGL(k_scan, dim3(BATCH * NC * DT), dim3(256), 0, stream,
                     u, A, delta, Bm, Cm, y, xend);
  hipLaunchKernelGGL(k_fix, dim3(BATCH * (NC - 1) * DT), dim3(256), 0, stream,
                     A, delta, Cm, xend, y);
}

// Round 5
// 138.752 us; speedup vs baseline: 1.7751x; 1.0166x over previous
//
#include <hip/hip_runtime.h>
#include <math.h>

// Selective SSM (Mamba-style) chunked-scan, round 5.
// Shapes: BATCH=4, SEQ=2048, D=768, N=16.  CHUNK=32 (NC=64).
//   k_proj : delta/B/C projections. Block = 8 rows, thread owns 4 W rows in
//            registers, u tile double-buffered in LDS. FMA-bound.
//   k_scan : CHUNK=32 -> 1536 blocks (6/CU, ~6 waves/SIMD for TLP).
//            u tile bulk-staged to LDS (no VMEM in the scan loop).
//            Thread pair owns (d, 8-of-16 states); y via shfl_xor(1).
//   k_fix  : fused carry walk-back + correction (uniform cutoff at
//            cum chunk-delta > 64: exp2 arg < -46 for all A <= -0.5 =>
//            contribution < 1e-9 vs 4.5e4 threshold).

#define BATCH 4
#define SEQ   2048
#define DDIM  768
#define NST   16
#define CHUNK 32
#define NC    (SEQ / CHUNK)      // 64
#define ROWS  (BATCH * SEQ)      // 8192
#define DT    (DDIM / 128)       // 6
#define LOG2E 1.4426950408889634f
#define FIX_THR 64.0f

__device__ __forceinline__ float fexp2(float x) {
#if __has_builtin(__builtin_amdgcn_exp2f)
  return __builtin_amdgcn_exp2f(x);
#else
  return exp2f(x);
#endif
}

// ---------------------------------------------------------------- k_proj ----
// 1024 blocks x 256 thr. Block = 8 rows. Thread (jg=tid>>5, ks=tid&31) owns
// output js {4jg..4jg+3} (+ q_delta for jg==0) and K-slice ks*4..+4 per tile.
__global__ __launch_bounds__(256) void k_proj(
    const float* __restrict__ u, const float* __restrict__ W_B,
    const float* __restrict__ W_C, const float* __restrict__ q_delta,
    const float* __restrict__ p_delta, float* __restrict__ delta,
    float* __restrict__ Bm, float* __restrict__ Cm) {
  __shared__ float u_s[2][8 * 128];     // 8 KB double-buffered u tile

  const int tid = threadIdx.x;
  const int jg  = tid >> 5;             // 0..7
  const int ks  = tid & 31;             // 0..31
  const int r0  = blockIdx.x * 8;

  const float* wrow[4];
#pragma unroll
  for (int jj = 0; jj < 4; ++jj) {
    const int j = jg * 4 + jj;
    wrow[jj] = (j < 16) ? (W_B + (size_t)j * DDIM)
                        : (W_C + (size_t)(j - 16) * DDIM);
  }

  const float* ubase = u + (size_t)r0 * DDIM;
  ((float4*)u_s[0])[tid] =
      *(const float4*)(ubase + (size_t)(tid >> 5) * DDIM + (tid & 31) * 4);

  float acc[4][8];
#pragma unroll
  for (int jj = 0; jj < 4; ++jj)
#pragma unroll
    for (int r = 0; r < 8; ++r) acc[jj][r] = 0.0f;
  float accd[8];
#pragma unroll
  for (int r = 0; r < 8; ++r) accd[r] = 0.0f;

  for (int kt = 0; kt < 6; ++kt) {
    __syncthreads();                    // u_s[kt&1] ready
    float4 nxt;
    if (kt < 5)
      nxt = *(const float4*)(ubase + (size_t)(tid >> 5) * DDIM +
                             (kt + 1) * 128 + (tid & 31) * 4);
    float4 w[4];
#pragma unroll
    for (int jj = 0; jj < 4; ++jj)
      w[jj] = *(const float4*)(wrow[jj] + kt * 128 + ks * 4);
    float4 qd = make_float4(0.f, 0.f, 0.f, 0.f);
    if (jg == 0) qd = *(const float4*)(q_delta + kt * 128 + ks * 4);

    const float4* us = (const float4*)u_s[kt & 1];
#pragma unroll
    for (int r = 0; r < 8; ++r) {
      const float4 uv = us[r * 32 + ks];
#pragma unroll
      for (int jj = 0; jj < 4; ++jj) {
        float s = acc[jj][r];
        s = fmaf(uv.x, w[jj].x, s); s = fmaf(uv.y, w[jj].y, s);
        s = fmaf(uv.z, w[jj].z, s); s = fmaf(uv.w, w[jj].w, s);
        acc[jj][r] = s;
      }
      if (jg == 0) {
        float s = accd[r];
        s = fmaf(uv.x, qd.x, s); s = fmaf(uv.y, qd.y, s);
        s = fmaf(uv.z, qd.z, s); s = fmaf(uv.w, qd.w, s);
        accd[r] = s;
      }
    }
    if (kt < 5) ((float4*)u_s[(kt + 1) & 1])[tid] = nxt;
  }

#pragma unroll
  for (int jj = 0; jj < 4; ++jj)
#pragma unroll
    for (int r = 0; r < 8; ++r) {
      float s = acc[jj][r];
      s += __shfl_xor(s, 1);  s += __shfl_xor(s, 2);
      s += __shfl_xor(s, 4);  s += __shfl_xor(s, 8);
      s += __shfl_xor(s, 16);
      acc[jj][r] = s;
    }
  if (jg == 0) {
#pragma unroll
    for (int r = 0; r < 8; ++r) {
      float s = accd[r];
      s += __shfl_xor(s, 1);  s += __shfl_xor(s, 2);
      s += __shfl_xor(s, 4);  s += __shfl_xor(s, 8);
      s += __shfl_xor(s, 16);
      accd[r] = s;
    }
  }

  if (ks == 0) {
#pragma unroll
    for (int jj = 0; jj < 4; ++jj) {
      const int j = jg * 4 + jj;
#pragma unroll
      for (int r = 0; r < 8; ++r) {
        const int row = r0 + r;
        if (j < 16) Bm[row * NST + j] = acc[jj][r];
        else        Cm[row * NST + (j - 16)] = acc[jj][r];
      }
    }
    if (jg == 0) {
      const float p = p_delta[0];
#pragma unroll
      for (int r = 0; r < 8; ++r) {
        const float z = p + accd[r];
        delta[r0 + r] = fmaxf(z, 0.0f) + log1pf(expf(-fabsf(z)));
      }
    }
  }
}

// ---------------------------------------------------------------- k_scan ----
// 1536 blocks x 256 thr. Thread (h=tid&1, dl=tid>>1) owns (d, states h*8..+8).
// All loop inputs staged in LDS; no VMEM inside the scan loop.
__global__ __launch_bounds__(256) void k_scan(
    const float* __restrict__ u, const float* __restrict__ A,
    const float* __restrict__ delta, const float* __restrict__ Bm,
    const float* __restrict__ Cm, float* __restrict__ y,
    float* __restrict__ xend) {
  __shared__ float u_s[CHUNK * 128];    // 16 KB
  __shared__ float Bs[CHUNK * NST];     // 2 KB
  __shared__ float Cs[CHUNK * NST];     // 2 KB
  __shared__ float sdelta[CHUNK];

  const int dt  = blockIdx.x % DT;
  const int c   = (blockIdx.x / DT) % NC;
  const int b   = blockIdx.x / (DT * NC);
  const int tid = threadIdx.x;
  const int h   = tid & 1;
  const int dl  = tid >> 1;
  const int d   = dt * 128 + dl;
  const int r0  = b * SEQ + c * CHUNK;

  {
    const float* ub = u + (size_t)r0 * DDIM + dt * 128;
#pragma unroll
    for (int t = 0; t < 4; ++t) {       // CHUNK*32 float4 = 1024
      const int idx = tid + t * 256;
      const int i = idx >> 5, f = idx & 31;
      ((float4*)u_s)[idx] = *(const float4*)(ub + (size_t)i * DDIM + f * 4);
    }
  }
  for (int i = tid; i < CHUNK * NST; i += 256) {
    Bs[i] = Bm[r0 * NST + i];
    Cs[i] = Cm[r0 * NST + i];
  }
  if (tid < CHUNK) sdelta[tid] = delta[r0 + tid];
  __syncthreads();

  float A2[8];
  {
    const float4* ap = (const float4*)(A + d * NST + h * 8);
    const float4 t0 = ap[0], t1 = ap[1];
    A2[0] = t0.x * LOG2E; A2[1] = t0.y * LOG2E;
    A2[2] = t0.z * LOG2E; A2[3] = t0.w * LOG2E;
    A2[4] = t1.x * LOG2E; A2[5] = t1.y * LOG2E;
    A2[6] = t1.z * LOG2E; A2[7] = t1.w * LOG2E;
  }
  float x[8];
#pragma unroll
  for (int n = 0; n < 8; ++n) x[n] = 0.0f;

  float* yp = y + (size_t)r0 * DDIM + d;

#pragma unroll 2
  for (int i = 0; i < CHUNK; ++i) {
    const float dlt = sdelta[i];
    const float du  = dlt * u_s[i * 128 + dl];

    const float4* Bp = (const float4*)(Bs + i * NST + h * 8);
    const float4* Cp = (const float4*)(Cs + i * NST + h * 8);
    const float4 b0 = Bp[0], b1 = Bp[1];
    const float4 c0 = Cp[0], c1 = Cp[1];
    const float bv[8] = {b0.x, b0.y, b0.z, b0.w, b1.x, b1.y, b1.z, b1.w};
    const float cv[8] = {c0.x, c0.y, c0.z, c0.w, c1.x, c1.y, c1.z, c1.w};

    float a0 = 0.0f, a1 = 0.0f;
#pragma unroll
    for (int n = 0; n < 8; ++n) {
      const float e = fexp2(A2[n] * dlt);
      x[n] = fmaf(e, x[n], du * bv[n]);
      if (n < 4) a0 = fmaf(x[n], cv[n], a0);
      else       a1 = fmaf(x[n], cv[n], a1);
    }
    float ys = a0 + a1;
    ys += __shfl_xor(ys, 1);
    if (h == 0) yp[(size_t)i * DDIM] = ys;
  }

  float4* xe =
      (float4*)(xend + ((size_t)((b * NC + c) * DDIM + d)) * NST + h * 8);
  xe[0] = make_float4(x[0], x[1], x[2], x[3]);
  xe[1] = make_float4(x[4], x[5], x[6], x[7]);
}

// ----------------------------------------------------------------- k_fix ----
// 1512 blocks x 256 thr; thread (h, dl) as in k_scan. Chunks 1..NC-1.
// Fused carry walk-back + correction pass.
__global__ __launch_bounds__(256) void k_fix(
    const float* __restrict__ A, const float* __restrict__ delta,
    const float* __restrict__ Cm, const float* __restrict__ xend,
    float* __restrict__ y) {
  __shared__ float sdelta[CHUNK];
  __shared__ float sDs;
  const int dt  = blockIdx.x % DT;
  const int c   = (blockIdx.x / DT) % (NC - 1) + 1;
  const int b   = blockIdx.x / (DT * (NC - 1));
  const int tid = threadIdx.x;
  const int h   = tid & 1;
  const int dl  = tid >> 1;
  const int d   = dt * 128 + dl;
  const int r0  = b * SEQ + c * CHUNK;

  if (tid < CHUNK) sdelta[tid] = delta[r0 + tid];

  float A2[8];
  {
    const float4* ap = (const float4*)(A + d * NST + h * 8);
    const float4 t0 = ap[0], t1 = ap[1];
    A2[0] = t0.x * LOG2E; A2[1] = t0.y * LOG2E;
    A2[2] = t0.z * LOG2E; A2[3] = t0.w * LOG2E;
    A2[4] = t1.x * LOG2E; A2[5] = t1.y * LOG2E;
    A2[6] = t1.z * LOG2E; A2[7] = t1.w * LOG2E;
  }

  // carry walk-back with uniform early cutoff.
  float carry[8]  = {0.f, 0.f, 0.f, 0.f, 0.f, 0.f, 0.f, 0.f};
  float factor[8] = {1.f, 1.f, 1.f, 1.f, 1.f, 1.f, 1.f, 1.f};
  float cumD = 0.0f;
  for (int cb = c - 1; cb >= 0; --cb) {
    const float4* cp = (const float4*)(
        xend + ((size_t)((b * NC + cb) * DDIM + d)) * NST + h * 8);
    const float4 q0 = cp[0], q1 = cp[1];
    carry[0] = fmaf(factor[0], q0.x, carry[0]);
    carry[1] = fmaf(factor[1], q0.y, carry[1]);
    carry[2] = fmaf(factor[2], q0.z, carry[2]);
    carry[3] = fmaf(factor[3], q0.w, carry[3]);
    carry[4] = fmaf(factor[4], q1.x, carry[4]);
    carry[5] = fmaf(factor[5], q1.y, carry[5]);
    carry[6] = fmaf(factor[6], q1.z, carry[6]);
    carry[7] = fmaf(factor[7], q1.w, carry[7]);

    __syncthreads();
    if (tid < 32) {
      float v = delta[b * SEQ + cb * CHUNK + tid];
      v += __shfl_xor(v, 1);  v += __shfl_xor(v, 2);
      v += __shfl_xor(v, 4);  v += __shfl_xor(v, 8);
      v += __shfl_xor(v, 16);
      if (tid == 0) sDs = v;
    }
    __syncthreads();
    const float Ds = sDs;
    cumD += Ds;
    if (cumD > FIX_THR) break;          // uniform across block
#pragma unroll
    for (int n = 0; n < 8; ++n) factor[n] *= fexp2(A2[n] * Ds);
  }
  // >=1 iteration ran (c>=1), each with two barriers -> sdelta visible.

  const float* Cp0 = Cm + (size_t)r0 * NST + h * 8;
  float* yp = y + (size_t)r0 * DDIM + d;

  float dS = 0.0f;
  for (int i = 0; i < CHUNK; ++i) {
    dS += sdelta[i];
    if (dS > FIX_THR) break;            // uniform across block
    const float4* Cp = (const float4*)(Cp0 + i * NST);
    const float4 c0 = Cp[0], c1 = Cp[1];
    const float cv[8] = {c0.x, c0.y, c0.z, c0.w, c1.x, c1.y, c1.z, c1.w};
    float a0 = 0.0f, a1 = 0.0f;
#pragma unroll
    for (int n = 0; n < 8; ++n) {
      const float e = fexp2(A2[n] * dS);
      if (n < 4) a0 = fmaf(e * carry[n], cv[n], a0);
      else       a1 = fmaf(e * carry[n], cv[n], a1);
    }
    float ys = a0 + a1;
    ys += __shfl_xor(ys, 1);
    if (h == 0) yp[(size_t)i * DDIM] += ys;
  }
}

// ------------------------------------------------------------------ launch --
extern "C" void kernel_launch(void* const* d_in, const int* in_sizes, int n_in,
                              void* d_out, int out_size, void* d_ws,
                              size_t ws_size, hipStream_t stream) {
  const float* u       = (const float*)d_in[0];
  const float* A       = (const float*)d_in[1];
  const float* W_B     = (const float*)d_in[2];
  const float* W_C     = (const float*)d_in[3];
  const float* q_delta = (const float*)d_in[4];
  const float* p_delta = (const float*)d_in[5];
  float* y  = (float*)d_out;
  float* ws = (float*)d_ws;

  float* delta = ws;                 // 8192
  float* Bm    = ws + 8192;          // 131072
  float* Cm    = ws + 139264;        // 131072
  float* xend  = ws + 270336;        // BATCH*NC*DDIM*NST = 3145728 (12.6 MB)

  hipLaunchKernelGGL(k_proj, dim3(ROWS / 8), dim3(256), 0, stream,
                     u, W_B, W_C, q_delta, p_delta, delta, Bm, Cm);
  hipLaunchKernelGGL(k_scan, dim3(BATCH * NC * DT), dim3(256), 0, stream,
                     u, A, delta, Bm, Cm, y, xend);
  hipLaunchKernelGGL(k_fix, dim3(BATCH * (NC - 1) * DT), dim3(256), 0, stream,
                     A, delta, Cm, xend, y);
}

// Round 6
// 136.718 us; speedup vs baseline: 1.8015x; 1.0149x over previous
//
#include <hip/hip_runtime.h>
#include <math.h>

// Selective SSM (Mamba-style) chunked-scan, round 6.
// Shapes: BATCH=4, SEQ=2048, D=768, N=16.  CHUNK=32 (NC=64).
//   k_proj : delta/B/C projections. Block = 8 rows, thread owns 4 W rows in
//            registers, u tile double-buffered in LDS. FMA-bound (~4 us,
//            at its 25-MB u-read HBM floor).
//   k_scan : 1536 blocks; u tile bulk-staged to LDS (no VMEM in scan loop).
//            Thread pair owns (d, 8-of-16 states). ALSO publishes per-chunk
//            delta-sum Dsum[b][c] (wave 0 of dt==0 blocks; sdelta is already
//            in LDS, so this is free).
//   k_fix  : fused carry walk-back + correction. Walk-back is now
//            BARRIER-FREE: chunk delta-sums come from Dsum[] (scalar L2-hot
//            loads) instead of a per-iteration 32-load + shfl-tree +
//            2x__syncthreads reduction. Uniform cutoff at cum chunk-delta
//            > 64 (exp2 arg < -46 for all A <= -0.5 => contribution < 1e-9
//            vs 4.5e4 threshold).

#define BATCH 4
#define SEQ   2048
#define DDIM  768
#define NST   16
#define CHUNK 32
#define NC    (SEQ / CHUNK)      // 64
#define ROWS  (BATCH * SEQ)      // 8192
#define DT    (DDIM / 128)       // 6
#define LOG2E 1.4426950408889634f
#define FIX_THR 64.0f

__device__ __forceinline__ float fexp2(float x) {
#if __has_builtin(__builtin_amdgcn_exp2f)
  return __builtin_amdgcn_exp2f(x);
#else
  return exp2f(x);
#endif
}

// ---------------------------------------------------------------- k_proj ----
// 1024 blocks x 256 thr. Block = 8 rows. Thread (jg=tid>>5, ks=tid&31) owns
// output js {4jg..4jg+3} (+ q_delta for jg==0) and K-slice ks*4..+4 per tile.
__global__ __launch_bounds__(256) void k_proj(
    const float* __restrict__ u, const float* __restrict__ W_B,
    const float* __restrict__ W_C, const float* __restrict__ q_delta,
    const float* __restrict__ p_delta, float* __restrict__ delta,
    float* __restrict__ Bm, float* __restrict__ Cm) {
  __shared__ float u_s[2][8 * 128];     // 8 KB double-buffered u tile

  const int tid = threadIdx.x;
  const int jg  = tid >> 5;             // 0..7
  const int ks  = tid & 31;             // 0..31
  const int r0  = blockIdx.x * 8;

  const float* wrow[4];
#pragma unroll
  for (int jj = 0; jj < 4; ++jj) {
    const int j = jg * 4 + jj;
    wrow[jj] = (j < 16) ? (W_B + (size_t)j * DDIM)
                        : (W_C + (size_t)(j - 16) * DDIM);
  }

  const float* ubase = u + (size_t)r0 * DDIM;
  ((float4*)u_s[0])[tid] =
      *(const float4*)(ubase + (size_t)(tid >> 5) * DDIM + (tid & 31) * 4);

  float acc[4][8];
#pragma unroll
  for (int jj = 0; jj < 4; ++jj)
#pragma unroll
    for (int r = 0; r < 8; ++r) acc[jj][r] = 0.0f;
  float accd[8];
#pragma unroll
  for (int r = 0; r < 8; ++r) accd[r] = 0.0f;

  for (int kt = 0; kt < 6; ++kt) {
    __syncthreads();                    // u_s[kt&1] ready
    float4 nxt;
    if (kt < 5)
      nxt = *(const float4*)(ubase + (size_t)(tid >> 5) * DDIM +
                             (kt + 1) * 128 + (tid & 31) * 4);
    float4 w[4];
#pragma unroll
    for (int jj = 0; jj < 4; ++jj)
      w[jj] = *(const float4*)(wrow[jj] + kt * 128 + ks * 4);
    float4 qd = make_float4(0.f, 0.f, 0.f, 0.f);
    if (jg == 0) qd = *(const float4*)(q_delta + kt * 128 + ks * 4);

    const float4* us = (const float4*)u_s[kt & 1];
#pragma unroll
    for (int r = 0; r < 8; ++r) {
      const float4 uv = us[r * 32 + ks];
#pragma unroll
      for (int jj = 0; jj < 4; ++jj) {
        float s = acc[jj][r];
        s = fmaf(uv.x, w[jj].x, s); s = fmaf(uv.y, w[jj].y, s);
        s = fmaf(uv.z, w[jj].z, s); s = fmaf(uv.w, w[jj].w, s);
        acc[jj][r] = s;
      }
      if (jg == 0) {
        float s = accd[r];
        s = fmaf(uv.x, qd.x, s); s = fmaf(uv.y, qd.y, s);
        s = fmaf(uv.z, qd.z, s); s = fmaf(uv.w, qd.w, s);
        accd[r] = s;
      }
    }
    if (kt < 5) ((float4*)u_s[(kt + 1) & 1])[tid] = nxt;
  }

#pragma unroll
  for (int jj = 0; jj < 4; ++jj)
#pragma unroll
    for (int r = 0; r < 8; ++r) {
      float s = acc[jj][r];
      s += __shfl_xor(s, 1);  s += __shfl_xor(s, 2);
      s += __shfl_xor(s, 4);  s += __shfl_xor(s, 8);
      s += __shfl_xor(s, 16);
      acc[jj][r] = s;
    }
  if (jg == 0) {
#pragma unroll
    for (int r = 0; r < 8; ++r) {
      float s = accd[r];
      s += __shfl_xor(s, 1);  s += __shfl_xor(s, 2);
      s += __shfl_xor(s, 4);  s += __shfl_xor(s, 8);
      s += __shfl_xor(s, 16);
      accd[r] = s;
    }
  }

  if (ks == 0) {
#pragma unroll
    for (int jj = 0; jj < 4; ++jj) {
      const int j = jg * 4 + jj;
#pragma unroll
      for (int r = 0; r < 8; ++r) {
        const int row = r0 + r;
        if (j < 16) Bm[row * NST + j] = acc[jj][r];
        else        Cm[row * NST + (j - 16)] = acc[jj][r];
      }
    }
    if (jg == 0) {
      const float p = p_delta[0];
#pragma unroll
      for (int r = 0; r < 8; ++r) {
        const float z = p + accd[r];
        delta[r0 + r] = fmaxf(z, 0.0f) + log1pf(expf(-fabsf(z)));
      }
    }
  }
}

// ---------------------------------------------------------------- k_scan ----
// 1536 blocks x 256 thr. Thread (h=tid&1, dl=tid>>1) owns (d, states h*8..+8).
// All loop inputs staged in LDS; no VMEM inside the scan loop.
// dt==0 blocks also publish Dsum[b*NC+c] = sum of this chunk's deltas.
__global__ __launch_bounds__(256) void k_scan(
    const float* __restrict__ u, const float* __restrict__ A,
    const float* __restrict__ delta, const float* __restrict__ Bm,
    const float* __restrict__ Cm, float* __restrict__ y,
    float* __restrict__ xend, float* __restrict__ Dsum) {
  __shared__ float u_s[CHUNK * 128];    // 16 KB
  __shared__ float Bs[CHUNK * NST];     // 2 KB
  __shared__ float Cs[CHUNK * NST];     // 2 KB
  __shared__ float sdelta[CHUNK];

  const int dt  = blockIdx.x % DT;
  const int c   = (blockIdx.x / DT) % NC;
  const int b   = blockIdx.x / (DT * NC);
  const int tid = threadIdx.x;
  const int h   = tid & 1;
  const int dl  = tid >> 1;
  const int d   = dt * 128 + dl;
  const int r0  = b * SEQ + c * CHUNK;

  {
    const float* ub = u + (size_t)r0 * DDIM + dt * 128;
#pragma unroll
    for (int t = 0; t < 4; ++t) {       // CHUNK*32 float4 = 1024
      const int idx = tid + t * 256;
      const int i = idx >> 5, f = idx & 31;
      ((float4*)u_s)[idx] = *(const float4*)(ub + (size_t)i * DDIM + f * 4);
    }
  }
  // B/C staging: CHUNK*NST = 512 floats = 128 float4 each
  if (tid < 128)       ((float4*)Bs)[tid]       = ((const float4*)(Bm + (size_t)r0 * NST))[tid];
  else if (tid < 256)  ((float4*)Cs)[tid - 128] = ((const float4*)(Cm + (size_t)r0 * NST))[tid - 128];
  if (tid < CHUNK) sdelta[tid] = delta[r0 + tid];
  __syncthreads();

  // publish chunk delta-sum (free: sdelta already resident)
  if (dt == 0 && tid < 32) {
    float v = sdelta[tid];
    v += __shfl_xor(v, 1);  v += __shfl_xor(v, 2);
    v += __shfl_xor(v, 4);  v += __shfl_xor(v, 8);
    v += __shfl_xor(v, 16);
    if (tid == 0) Dsum[b * NC + c] = v;
  }

  float A2[8];
  {
    const float4* ap = (const float4*)(A + d * NST + h * 8);
    const float4 t0 = ap[0], t1 = ap[1];
    A2[0] = t0.x * LOG2E; A2[1] = t0.y * LOG2E;
    A2[2] = t0.z * LOG2E; A2[3] = t0.w * LOG2E;
    A2[4] = t1.x * LOG2E; A2[5] = t1.y * LOG2E;
    A2[6] = t1.z * LOG2E; A2[7] = t1.w * LOG2E;
  }
  float x[8];
#pragma unroll
  for (int n = 0; n < 8; ++n) x[n] = 0.0f;

  float* yp = y + (size_t)r0 * DDIM + d;

#pragma unroll 2
  for (int i = 0; i < CHUNK; ++i) {
    const float dlt = sdelta[i];
    const float du  = dlt * u_s[i * 128 + dl];

    const float4* Bp = (const float4*)(Bs + i * NST + h * 8);
    const float4* Cp = (const float4*)(Cs + i * NST + h * 8);
    const float4 b0 = Bp[0], b1 = Bp[1];
    const float4 c0 = Cp[0], c1 = Cp[1];
    const float bv[8] = {b0.x, b0.y, b0.z, b0.w, b1.x, b1.y, b1.z, b1.w};
    const float cv[8] = {c0.x, c0.y, c0.z, c0.w, c1.x, c1.y, c1.z, c1.w};

    float a0 = 0.0f, a1 = 0.0f;
#pragma unroll
    for (int n = 0; n < 8; ++n) {
      const float e = fexp2(A2[n] * dlt);
      x[n] = fmaf(e, x[n], du * bv[n]);
      if (n < 4) a0 = fmaf(x[n], cv[n], a0);
      else       a1 = fmaf(x[n], cv[n], a1);
    }
    float ys = a0 + a1;
    ys += __shfl_xor(ys, 1);
    if (h == 0) yp[(size_t)i * DDIM] = ys;
  }

  float4* xe =
      (float4*)(xend + ((size_t)((b * NC + c) * DDIM + d)) * NST + h * 8);
  xe[0] = make_float4(x[0], x[1], x[2], x[3]);
  xe[1] = make_float4(x[4], x[5], x[6], x[7]);
}

// ----------------------------------------------------------------- k_fix ----
// 1512 blocks x 256 thr; thread (h, dl) as in k_scan. Chunks 1..NC-1.
// Fused carry walk-back (barrier-free, Dsum-based) + correction pass.
__global__ __launch_bounds__(256) void k_fix(
    const float* __restrict__ A, const float* __restrict__ delta,
    const float* __restrict__ Cm, const float* __restrict__ xend,
    const float* __restrict__ Dsum, float* __restrict__ y) {
  __shared__ float sdelta[CHUNK];
  const int dt  = blockIdx.x % DT;
  const int c   = (blockIdx.x / DT) % (NC - 1) + 1;
  const int b   = blockIdx.x / (DT * (NC - 1));
  const int tid = threadIdx.x;
  const int h   = tid & 1;
  const int dl  = tid >> 1;
  const int d   = dt * 128 + dl;
  const int r0  = b * SEQ + c * CHUNK;

  if (tid < CHUNK) sdelta[tid] = delta[r0 + tid];

  float A2[8];
  {
    const float4* ap = (const float4*)(A + d * NST + h * 8);
    const float4 t0 = ap[0], t1 = ap[1];
    A2[0] = t0.x * LOG2E; A2[1] = t0.y * LOG2E;
    A2[2] = t0.z * LOG2E; A2[3] = t0.w * LOG2E;
    A2[4] = t1.x * LOG2E; A2[5] = t1.y * LOG2E;
    A2[6] = t1.z * LOG2E; A2[7] = t1.w * LOG2E;
  }

  // carry walk-back: barrier-free. carry = sum_j (prod P) * xend[c-j],
  // uniform early cutoff on cumulative chunk delta-sum.
  float carry[8]  = {0.f, 0.f, 0.f, 0.f, 0.f, 0.f, 0.f, 0.f};
  float factor[8] = {1.f, 1.f, 1.f, 1.f, 1.f, 1.f, 1.f, 1.f};
  float cumD = 0.0f;
  for (int cb = c - 1; cb >= 0; --cb) {
    const float4* cp = (const float4*)(
        xend + ((size_t)((b * NC + cb) * DDIM + d)) * NST + h * 8);
    const float4 q0 = cp[0], q1 = cp[1];
    carry[0] = fmaf(factor[0], q0.x, carry[0]);
    carry[1] = fmaf(factor[1], q0.y, carry[1]);
    carry[2] = fmaf(factor[2], q0.z, carry[2]);
    carry[3] = fmaf(factor[3], q0.w, carry[3]);
    carry[4] = fmaf(factor[4], q1.x, carry[4]);
    carry[5] = fmaf(factor[5], q1.y, carry[5]);
    carry[6] = fmaf(factor[6], q1.z, carry[6]);
    carry[7] = fmaf(factor[7], q1.w, carry[7]);

    const float Ds = Dsum[b * NC + cb];  // scalar, L2-hot
    cumD += Ds;
    if (cumD > FIX_THR) break;           // uniform across block
#pragma unroll
    for (int n = 0; n < 8; ++n) factor[n] *= fexp2(A2[n] * Ds);
  }
  __syncthreads();                       // sdelta visible

  const float* Cp0 = Cm + (size_t)r0 * NST + h * 8;
  float* yp = y + (size_t)r0 * DDIM + d;

  float dS = 0.0f;
  for (int i = 0; i < CHUNK; ++i) {
    dS += sdelta[i];
    if (dS > FIX_THR) break;             // uniform across block
    const float4* Cp = (const float4*)(Cp0 + i * NST);
    const float4 c0 = Cp[0], c1 = Cp[1];
    const float cv[8] = {c0.x, c0.y, c0.z, c0.w, c1.x, c1.y, c1.z, c1.w};
    float a0 = 0.0f, a1 = 0.0f;
#pragma unroll
    for (int n = 0; n < 8; ++n) {
      const float e = fexp2(A2[n] * dS);
      if (n < 4) a0 = fmaf(e * carry[n], cv[n], a0);
      else       a1 = fmaf(e * carry[n], cv[n], a1);
    }
    float ys = a0 + a1;
    ys += __shfl_xor(ys, 1);
    if (h == 0) yp[(size_t)i * DDIM] += ys;
  }
}

// ------------------------------------------------------------------ launch --
extern "C" void kernel_launch(void* const* d_in, const int* in_sizes, int n_in,
                              void* d_out, int out_size, void* d_ws,
                              size_t ws_size, hipStream_t stream) {
  const float* u       = (const float*)d_in[0];
  const float* A       = (const float*)d_in[1];
  const float* W_B     = (const float*)d_in[2];
  const float* W_C     = (const float*)d_in[3];
  const float* q_delta = (const float*)d_in[4];
  const float* p_delta = (const float*)d_in[5];
  float* y  = (float*)d_out;
  float* ws = (float*)d_ws;

  float* delta = ws;                 // 8192
  float* Bm    = ws + 8192;          // 131072
  float* Cm    = ws + 139264;        // 131072
  float* xend  = ws + 270336;        // BATCH*NC*DDIM*NST = 3145728 (12.6 MB)
  float* Dsum  = ws + 270336 + 3145728;  // BATCH*NC = 256

  hipLaunchKernelGGL(k_proj, dim3(ROWS / 8), dim3(256), 0, stream,
                     u, W_B, W_C, q_delta, p_delta, delta, Bm, Cm);
  hipLaunchKernelGGL(k_scan, dim3(BATCH * NC * DT), dim3(256), 0, stream,
                     u, A, delta, Bm, Cm, y, xend, Dsum);
  hipLaunchKernelGGL(k_fix, dim3(BATCH * (NC - 1) * DT), dim3(256), 0, stream,
                     A, delta, Cm, xend, Dsum, y);
}